// Round 6
// baseline (253.856 us; speedup 1.0000x reference)
//
#include <hip/hip_runtime.h>
#include <hip/hip_bf16.h>
#include <math.h>

// Problem constants: N=2, D=384, 2U=256, nH=8, hd=48, nL=4, nP=4
#define DM   384
#define U2   256
#define HD   48

typedef __attribute__((ext_vector_type(8))) short short8;   // 8 bf16 = 4 VGPR
typedef __attribute__((ext_vector_type(4))) float floatx4;  // MFMA acc

static __device__ __forceinline__ unsigned short f2bfbits(float f) {
    __hip_bfloat16 h = __float2bfloat16(f);
    return *reinterpret_cast<unsigned short*>(&h);
}
static __device__ __forceinline__ unsigned pack2(float x, float y) {
    return (unsigned)f2bfbits(x) | ((unsigned)f2bfbits(y) << 16);
}
static __device__ __forceinline__ float bflo(unsigned u) { return __uint_as_float(u << 16); }
static __device__ __forceinline__ float bfhi(unsigned u) { return __uint_as_float(u & 0xffff0000u); }

// async global->LDS, 16B per lane; LDS dst is wave-uniform base + lane*16
#define GLDS16(g, l)  __builtin_amdgcn_global_load_lds(                        \
    (const __attribute__((address_space(1))) unsigned int*)(g),                \
    (__attribute__((address_space(3))) unsigned int*)(l), 16, 0, 0)

// =====================================================================
// Prep: query->bf16, flat->bf16, 7 weight transposes (fp32->bf16).
// =====================================================================
struct PrepParams {
    const float* q; const float* f;
    __hip_bfloat16 *q_bf, *f_bf;
    const float* wsrc[7]; __hip_bfloat16* wdst[7];
    int K[7], N[7], off[8];
    int nQ4, nF4, total;
};
__global__ __launch_bounds__(256) void prep_kernel(PrepParams d) {
    const int idx = blockIdx.x * 256 + threadIdx.x;
    if (idx >= d.total) return;
    if (idx < d.nQ4) {
        const int i4 = idx * 4;
        const float4 v = *(const float4*)&d.q[i4];
        uint2 pk; pk.x = pack2(v.x, v.y); pk.y = pack2(v.z, v.w);
        *(uint2*)&d.q_bf[i4] = pk;
        return;
    }
    if (idx < d.nQ4 + d.nF4) {
        const int i4 = (idx - d.nQ4) * 4;
        const float4 v = *(const float4*)&d.f[i4];
        uint2 pk; pk.x = pack2(v.x, v.y); pk.y = pack2(v.z, v.w);
        *(uint2*)&d.f_bf[i4] = pk;
        return;
    }
    const int iw = idx - d.nQ4 - d.nF4;
    int s = 0;
#pragma unroll
    for (int i = 1; i < 7; ++i) if (iw >= d.off[i]) s = i;
    const int r = iw - d.off[s];
    const int k = r / d.N[s], n = r - k * d.N[s];
    d.wdst[s][(size_t)n * d.K[s] + k] = __float2bfloat16(d.wsrc[s][r]);
}

// =====================================================================
// Multi-segment bf16 MFMA GEMM, m97 recipe:
//   - 128x128 tile, BK=32, unpadded 64B LDS rows
//   - global_load_lds dwordx4 staging (no VGPR roundtrip)
//   - wave w stages A rows [32w,32w+32) and B rows [32w,32w+32)
// omode: 0 = f32 out; 1 = bf16 out; 2/3 = bf16 scatter into combined
// value layout (top/bot): idx = row*768 + (col/48)*96 + (omode==3)*48 + col%48
// =====================================================================
struct Seg {
    const __hip_bfloat16* A; int lda;
    const __hip_bfloat16* Bt; int ldbt;
    const float* bias; void* C; int ldc; int K; int omode;
};
struct SegParams { Seg seg[5]; int ystart[5]; int nseg; };

__global__ __launch_bounds__(256) void gemm_seg_kernel(SegParams p) {
    __shared__ __hip_bfloat16 As[128 * 32];
    __shared__ __hip_bfloat16 Bs[128 * 32];

    const int yb = blockIdx.y;
    int s = 0;
#pragma unroll
    for (int i = 1; i < 5; ++i) if (i < p.nseg && yb >= p.ystart[i]) s = i;
    Seg sg;
    switch (s) {
        case 0: sg = p.seg[0]; break;
        case 1: sg = p.seg[1]; break;
        case 2: sg = p.seg[2]; break;
        case 3: sg = p.seg[3]; break;
        default: sg = p.seg[4]; break;
    }
    const int by = yb - p.ystart[s];

    const int t    = threadIdx.x;
    const int bm   = blockIdx.x * 128;
    const int bn   = by * 128;
    const int w    = t >> 6, lane = t & 63;
    const int wm   = (w >> 1) * 64, wn = (w & 1) * 64;
    const int quad = lane >> 4, lm = lane & 15;

    // staging map: lane l -> row_local = l>>2, k-chunk = (l&3)*8 elems
    const int sr = lane >> 2;
    const int sc = (lane & 3) * 8;

    // per-wave A/B row bases (two 16-row instrs per operand)
    const __hip_bfloat16* Ag0 = sg.A  + (size_t)(bm + 32 * w + sr) * sg.lda  + sc;
    const __hip_bfloat16* Ag1 = sg.A  + (size_t)(bm + 32 * w + 16 + sr) * sg.lda  + sc;
    const __hip_bfloat16* Bg0 = sg.Bt + (size_t)(bn + 32 * w + sr) * sg.ldbt + sc;
    const __hip_bfloat16* Bg1 = sg.Bt + (size_t)(bn + 32 * w + 16 + sr) * sg.ldbt + sc;
    __hip_bfloat16* Al0 = As + (32 * w) * 32;
    __hip_bfloat16* Al1 = As + (32 * w + 16) * 32;
    __hip_bfloat16* Bl0 = Bs + (32 * w) * 32;
    __hip_bfloat16* Bl1 = Bs + (32 * w + 16) * 32;

    floatx4 acc[4][4] = {};

    for (int k0 = 0; k0 < sg.K; k0 += 32) {
        GLDS16(Ag0 + k0, Al0);
        GLDS16(Ag1 + k0, Al1);
        GLDS16(Bg0 + k0, Bl0);
        GLDS16(Bg1 + k0, Bl1);
        __syncthreads();

        short8 af[4], bf[4];
#pragma unroll
        for (int i = 0; i < 4; ++i)
            af[i] = *(const short8*)&As[(wm + i * 16 + lm) * 32 + quad * 8];
#pragma unroll
        for (int j = 0; j < 4; ++j)
            bf[j] = *(const short8*)&Bs[(wn + j * 16 + lm) * 32 + quad * 8];
#pragma unroll
        for (int i = 0; i < 4; ++i)
#pragma unroll
            for (int j = 0; j < 4; ++j)
                acc[i][j] = __builtin_amdgcn_mfma_f32_16x16x32_bf16(
                    af[i], bf[j], acc[i][j], 0, 0, 0);
        __syncthreads();
    }

#pragma unroll
    for (int i = 0; i < 4; ++i)
#pragma unroll
        for (int reg = 0; reg < 4; ++reg) {
            const int row = bm + wm + i * 16 + quad * 4 + reg;
#pragma unroll
            for (int j = 0; j < 4; ++j) {
                const int col = bn + wn + j * 16 + lm;
                const float v = acc[i][j][reg] + sg.bias[col];
                if (sg.omode == 0) {
                    ((float*)sg.C)[(size_t)row * sg.ldc + col] = v;
                } else if (sg.omode == 1) {
                    ((__hip_bfloat16*)sg.C)[(size_t)row * sg.ldc + col] = __float2bfloat16(v);
                } else {
                    const int h = col / 48;
                    const size_t idx = (size_t)row * 768 + h * 96 +
                                       ((sg.omode == 3) ? 48 : 0) + (col - h * 48);
                    ((__hip_bfloat16*)sg.C)[idx] = __float2bfloat16(v);
                }
            }
        }
}

// =====================================================================
// Fused sampler, 4 queries per 384-thread block (6 waves -> ~30 waves/CU
// resident: hide L2/L3 gather-miss latency).
// Geometry items: item = q*128 + e (512 items): slot0 = item t (all 384),
// slot1 = item 384+t (t<128). Softmax: t<64 covers (q,br,h).
// Phase 3: 96 threads/query; (br,h) group of 6 threads; uint4 gathers from
// combined value layout (point row 1536B = [h][br][48ch]); 12 consecutive
// lanes read one contiguous 192B segment (3 cache lines).
// =====================================================================
#define SPP 524

__global__ __launch_bounds__(384) void sampler_kernel(
    const float* __restrict__ off_buf,    // (M, 256) fp32
    const float* __restrict__ logit_top,  // (M, 128)
    const float* __restrict__ logit_bot,  // (M, 128)
    const float* __restrict__ ref_pts,    // (M, 4, 2)
    const int*   __restrict__ ss,         // (4,2) [H,W]
    const int*   __restrict__ lsi,        // (4,)
    const __hip_bfloat16* __restrict__ vcomb,  // (Mv, 768) combined
    __hip_bfloat16* __restrict__ core_top,     // (M, 384) bf16
    __hip_bfloat16* __restrict__ core_bot,     // (M, 384) bf16
    int Lq, int LenIn)
{
    __shared__ float    sA[8][128];   // [q*2+br][e]
    __shared__ unsigned sP[8][SPP];   // packed (bf16 w)<<16 | point

    const int bid = blockIdx.x;
    const int Q0  = bid * 4;
    const int t   = threadIdx.x;

    float gw[2][4];
    int   gp[2][4];
#pragma unroll
    for (int slot = 0; slot < 2; ++slot) {
        if (slot && t >= 128) continue;
        const int q = slot ? 3 : (t >> 7);
        const int e = slot ? t : (t & 127);
        const int gq = Q0 + q;
        const int n  = gq / Lq;
        const int l  = (e >> 2) & 3;
        const float2 offv = *(const float2*)&off_buf[(size_t)gq * 256 + 2 * e];
        const float rx = ref_pts[(size_t)(gq * 4 + l) * 2 + 0];
        const float ry = ref_pts[(size_t)(gq * 4 + l) * 2 + 1];
        const int H = ss[2 * l], W = ss[2 * l + 1];
        const int start = lsi[l];

        const float x = (rx + offv.x / (float)W) * (float)W - 0.5f;
        const float y = (ry + offv.y / (float)H) * (float)H - 0.5f;
        const float x0f = floorf(x), y0f = floorf(y);
        const float lx = x - x0f, ly = y - y0f;
        const int ix0 = (int)x0f, iy0 = (int)y0f;
        const int ix1 = ix0 + 1,  iy1 = iy0 + 1;

        const float vx0 = (ix0 >= 0 && ix0 < W) ? 1.f : 0.f;
        const float vx1 = (ix1 >= 0 && ix1 < W) ? 1.f : 0.f;
        const float vy0 = (iy0 >= 0 && iy0 < H) ? 1.f : 0.f;
        const float vy1 = (iy1 >= 0 && iy1 < H) ? 1.f : 0.f;
        const int cx0 = min(max(ix0, 0), W - 1);
        const int cx1 = min(max(ix1, 0), W - 1);
        const int cy0 = min(max(iy0, 0), H - 1);
        const int cy1 = min(max(iy1, 0), H - 1);
        const int base = n * LenIn + start;

        gp[slot][0] = base + cy0 * W + cx0;
        gp[slot][1] = base + cy0 * W + cx1;
        gp[slot][2] = base + cy1 * W + cx0;
        gp[slot][3] = base + cy1 * W + cx1;
        gw[slot][0] = (1.f - lx) * (1.f - ly) * vx0 * vy0;
        gw[slot][1] = lx * (1.f - ly) * vx1 * vy0;
        gw[slot][2] = (1.f - lx) * ly * vx0 * vy1;
        gw[slot][3] = lx * ly * vx1 * vy1;
    }

    // ---- softmax: t<64 -> (q = t>>4, br = (t>>3)&1, h = t&7) ----
    if (t < 64) {
        const int q  = t >> 4;
        const int br = (t >> 3) & 1;
        const int h  = t & 7;
        const float* L = (br ? logit_bot : logit_top) + (size_t)(Q0 + q) * 128 + h * 16;
        float lg[16];
        *(float4*)&lg[0]  = *(const float4*)&L[0];
        *(float4*)&lg[4]  = *(const float4*)&L[4];
        *(float4*)&lg[8]  = *(const float4*)&L[8];
        *(float4*)&lg[12] = *(const float4*)&L[12];
        float m = -1e30f;
#pragma unroll
        for (int j = 0; j < 16; ++j) m = fmaxf(m, lg[j]);
        float ex[16], sum = 0.f;
#pragma unroll
        for (int j = 0; j < 16; ++j) { ex[j] = expf(lg[j] - m); sum += ex[j]; }
        const float inv = 1.f / sum;
#pragma unroll
        for (int j = 0; j < 16; ++j) sA[q * 2 + br][h * 16 + j] = ex[j] * inv;
    }
    __syncthreads();

    // ---- pack premultiplied weights + point indices ----
#pragma unroll
    for (int slot = 0; slot < 2; ++slot) {
        if (slot && t >= 128) continue;
        const int q = slot ? 3 : (t >> 7);
        const int e = slot ? t : (t & 127);
        const int pidx = 4 * e + (e >> 4);
#pragma unroll
        for (int br = 0; br < 2; ++br) {
            const float a = sA[q * 2 + br][e];
#pragma unroll
            for (int k = 0; k < 4; ++k) {
                sP[q * 2 + br][pidx + k] =
                    ((unsigned)f2bfbits(gw[slot][k] * a) << 16) | (unsigned)gp[slot][k];
            }
        }
    }
    __syncthreads();

    // ---- phase 3: gathers ----
    const int q  = t / 96;
    const int r  = t - q * 96;
    const int g  = r / 6;
    const int m  = r - g * 6;
    const int br = g & 1;
    const int h  = g >> 1;

    const unsigned* P = sP[q * 2 + br];
    const char* vb = (const char*)vcomb + h * 192 + br * 96 + m * 16;

    float a0 = 0.f, a1 = 0.f, a2 = 0.f, a3 = 0.f;
    float a4 = 0.f, a5 = 0.f, a6 = 0.f, a7 = 0.f;
#pragma unroll 4
    for (int lp = 0; lp < 16; ++lp) {
        const int ib = 65 * h + 4 * lp;
#pragma unroll
        for (int k = 0; k < 4; ++k) {
            const unsigned u = P[ib + k];
            const float wv = __uint_as_float(u & 0xffff0000u);
            const unsigned pt = u & 0x3fffu;
            const uint4 v = *(const uint4*)(vb + pt * 1536u);
            a0 = fmaf(wv, bflo(v.x), a0);
            a1 = fmaf(wv, bfhi(v.x), a1);
            a2 = fmaf(wv, bflo(v.y), a2);
            a3 = fmaf(wv, bfhi(v.y), a3);
            a4 = fmaf(wv, bflo(v.z), a4);
            a5 = fmaf(wv, bfhi(v.z), a5);
            a6 = fmaf(wv, bflo(v.w), a6);
            a7 = fmaf(wv, bfhi(v.w), a7);
        }
    }
    uint4 o;
    o.x = pack2(a0, a1); o.y = pack2(a2, a3);
    o.z = pack2(a4, a5); o.w = pack2(a6, a7);
    __hip_bfloat16* dst = br ? core_bot : core_top;
    *(uint4*)&dst[(size_t)(Q0 + q) * DM + h * HD + m * 8] = o;
}

// =====================================================================
// Host launcher
// =====================================================================
extern "C" void kernel_launch(void* const* d_in, const int* in_sizes, int n_in,
                              void* d_out, int out_size, void* d_ws, size_t ws_size,
                              hipStream_t stream) {
    const float* query   = (const float*)d_in[0];
    const float* refpts  = (const float*)d_in[1];
    const float* flat    = (const float*)d_in[2];
    const int*   ss      = (const int*)d_in[3];
    const int*   lsi     = (const int*)d_in[4];
    const float* W_off   = (const float*)d_in[5];
    const float* b_off   = (const float*)d_in[6];
    const float* W_attn  = (const float*)d_in[7];
    const float* b_attn  = (const float*)d_in[8];
    const float* W_val   = (const float*)d_in[9];
    const float* b_val   = (const float*)d_in[10];
    const float* W_out   = (const float*)d_in[11];
    const float* b_out   = (const float*)d_in[12];
    const float* W_attn_zd = (const float*)d_in[13];
    const float* b_attn_zd = (const float*)d_in[14];
    const float* W_val_zd  = (const float*)d_in[15];
    const float* b_val_zd  = (const float*)d_in[16];
    const float* W_out_zd  = (const float*)d_in[17];
    const float* b_out_zd  = (const float*)d_in[18];

    const int Lq    = in_sizes[0] / (2 * DM);   // 5440
    const int LenIn = in_sizes[2] / (2 * DM);   // 5440
    const int M  = 2 * Lq;      // 10880
    const int Mv = 2 * LenIn;   // 10880

    float* out = (float*)d_out;

    // ---- workspace layout ----
    float* ws      = (float*)d_ws;
    float* off_buf = ws;                               // M*256 f32
    float* lt      = off_buf + (size_t)M * 256;        // M*128 f32
    float* lb      = lt + (size_t)M * 128;             // M*128 f32
    __hip_bfloat16* q_bf  = (__hip_bfloat16*)(lb + (size_t)M * 128); // M*384
    __hip_bfloat16* f_bf  = q_bf + (size_t)M * 384;    // Mv*384
    __hip_bfloat16* vcomb = f_bf + (size_t)Mv * 384;   // Mv*768 combined
    __hip_bfloat16* ct    = vcomb + (size_t)Mv * 768;  // M*384
    __hip_bfloat16* cb    = ct + (size_t)M * 384;      // M*384
    __hip_bfloat16* wtb   = cb + (size_t)M * 384;      // weights

    // ---- prep params (7 weight transposes incl. W_off) ----
    PrepParams pp;
    pp.q = query; pp.f = flat;
    pp.q_bf = q_bf; pp.f_bf = f_bf;
    const float* srcs[7] = {W_attn, W_attn_zd, W_val, W_val_zd, W_out, W_out_zd, W_off};
    const int Ks[7] = {256, 384, 256, 384, 384, 384, 256};
    const int Ns[7] = {128, 128, 384, 384, 256, 128, 256};
    __hip_bfloat16* dsts[7];
    int off = 0;
    for (int i = 0; i < 7; ++i) {
        pp.wsrc[i] = srcs[i]; pp.K[i] = Ks[i]; pp.N[i] = Ns[i];
        pp.off[i] = off;
        dsts[i] = wtb + off;
        pp.wdst[i] = dsts[i];
        off += Ks[i] * Ns[i];
    }
    pp.off[7] = off;
    pp.nQ4 = M * DM / 4;
    pp.nF4 = Mv * DM / 4;
    pp.total = pp.nQ4 + pp.nF4 + off;

    const dim3 blk(256);
    const int mg = M / 128;   // 85

    prep_kernel<<<dim3((pp.total + 255) / 256), blk, 0, stream>>>(pp);

    // ---- MEGA-GEMM 1: off + logits + values(combined scatter), grid (85,10)
    {
        SegParams p;
        p.seg[0] = { q_bf, DM, dsts[6], 256, b_off,    off_buf, 256, 256, 0 }; // y0-1
        p.seg[1] = { q_bf, DM, dsts[0], 256, b_attn,   lt,      128, 256, 0 }; // y2
        p.seg[2] = { q_bf, DM, dsts[1], 384, b_attn_zd,lb,      128, 384, 0 }; // y3
        p.seg[3] = { f_bf, DM, dsts[2], 256, b_val,    vcomb,   0,   256, 2 }; // y4-6 top
        p.seg[4] = { f_bf, DM, dsts[3], 384, b_val_zd, vcomb,   0,   384, 3 }; // y7-9 bot
        p.ystart[0] = 0; p.ystart[1] = 2; p.ystart[2] = 3;
        p.ystart[3] = 4; p.ystart[4] = 7;
        p.nseg = 5;
        gemm_seg_kernel<<<dim3(mg, 10), blk, 0, stream>>>(p);
    }

    // ---- sampler: 4 queries per 384-thread block ----
    sampler_kernel<<<dim3(M / 4), dim3(384), 0, stream>>>(
        off_buf, lt, lb, refpts, ss, lsi, vcomb, ct, cb, Lq, LenIn);

    // ---- MEGA-GEMM 2: output projections, grid (85,3) ----
    {
        SegParams p;
        p.seg[0] = { ct, DM, dsts[4], 384, b_out,    out,      DM, 384, 0 }; // y0-1
        p.seg[1] = { cb, DM, dsts[5], 384, b_out_zd, out + U2, DM, 384, 0 }; // y2
        p.ystart[0] = 0; p.ystart[1] = 2;
        p.nseg = 2;
        gemm_seg_kernel<<<dim3(mg, 3), blk, 0, stream>>>(p);
    }
}

// Round 7
// 253.511 us; speedup vs baseline: 1.0014x; 1.0014x over previous
//
#include <hip/hip_runtime.h>
#include <hip/hip_bf16.h>
#include <math.h>

// Problem constants: N=2, D=384, 2U=256, nH=8, hd=48, nL=4, nP=4
#define DM   384
#define U2   256
#define HD   48

typedef __attribute__((ext_vector_type(8))) short short8;   // 8 bf16 = 4 VGPR
typedef __attribute__((ext_vector_type(4))) float floatx4;  // MFMA acc

static __device__ __forceinline__ unsigned short f2bfbits(float f) {
    __hip_bfloat16 h = __float2bfloat16(f);
    return *reinterpret_cast<unsigned short*>(&h);
}
static __device__ __forceinline__ unsigned pack2(float x, float y) {
    return (unsigned)f2bfbits(x) | ((unsigned)f2bfbits(y) << 16);
}
static __device__ __forceinline__ float bflo(unsigned u) { return __uint_as_float(u << 16); }
static __device__ __forceinline__ float bfhi(unsigned u) { return __uint_as_float(u & 0xffff0000u); }

// async global->LDS, 16B per lane; LDS dst is wave-uniform base + lane*16
#define GLDS16(g, l)  __builtin_amdgcn_global_load_lds(                        \
    (const __attribute__((address_space(1))) unsigned int*)(g),                \
    (__attribute__((address_space(3))) unsigned int*)(l), 16, 0, 0)

// =====================================================================
// Prep: query->bf16, flat->bf16, 7 weight transposes (fp32->bf16).
// =====================================================================
struct PrepParams {
    const float* q; const float* f;
    __hip_bfloat16 *q_bf, *f_bf;
    const float* wsrc[7]; __hip_bfloat16* wdst[7];
    int K[7], N[7], off[8];
    int nQ4, nF4, total;
};
__global__ __launch_bounds__(256) void prep_kernel(PrepParams d) {
    const int idx = blockIdx.x * 256 + threadIdx.x;
    if (idx >= d.total) return;
    if (idx < d.nQ4) {
        const int i4 = idx * 4;
        const float4 v = *(const float4*)&d.q[i4];
        uint2 pk; pk.x = pack2(v.x, v.y); pk.y = pack2(v.z, v.w);
        *(uint2*)&d.q_bf[i4] = pk;
        return;
    }
    if (idx < d.nQ4 + d.nF4) {
        const int i4 = (idx - d.nQ4) * 4;
        const float4 v = *(const float4*)&d.f[i4];
        uint2 pk; pk.x = pack2(v.x, v.y); pk.y = pack2(v.z, v.w);
        *(uint2*)&d.f_bf[i4] = pk;
        return;
    }
    const int iw = idx - d.nQ4 - d.nF4;
    int s = 0;
#pragma unroll
    for (int i = 1; i < 7; ++i) if (iw >= d.off[i]) s = i;
    const int r = iw - d.off[s];
    const int k = r / d.N[s], n = r - k * d.N[s];
    d.wdst[s][(size_t)n * d.K[s] + k] = __float2bfloat16(d.wsrc[s][r]);
}

// =====================================================================
// Multi-segment bf16 MFMA GEMM (m97 recipe + XOR chunk swizzle):
//   - 128x128 tile, BK=32, unpadded 64B LDS rows (GLDS16-compatible)
//   - physical 16B chunk p of row r holds GLOBAL chunk p ^ ((r>>1)&3)
//     => fragment ds_read_b128 banks spread over all 32 banks (2-way, free)
//   - global_load_lds dwordx4 staging (no VGPR roundtrip)
// omode: 0 = f32 out; 1 = bf16 out; 2/3 = bf16 scatter into combined
// value layout (top/bot): idx = row*768 + (col/48)*96 + (omode==3)*48 + col%48
// =====================================================================
struct Seg {
    const __hip_bfloat16* A; int lda;
    const __hip_bfloat16* Bt; int ldbt;
    const float* bias; void* C; int ldc; int K; int omode;
};
struct SegParams { Seg seg[5]; int ystart[5]; int nseg; };

__global__ __launch_bounds__(256) void gemm_seg_kernel(SegParams p) {
    __shared__ __hip_bfloat16 As[128 * 32];
    __shared__ __hip_bfloat16 Bs[128 * 32];

    const int yb = blockIdx.y;
    int s = 0;
#pragma unroll
    for (int i = 1; i < 5; ++i) if (i < p.nseg && yb >= p.ystart[i]) s = i;
    Seg sg;
    switch (s) {
        case 0: sg = p.seg[0]; break;
        case 1: sg = p.seg[1]; break;
        case 2: sg = p.seg[2]; break;
        case 3: sg = p.seg[3]; break;
        default: sg = p.seg[4]; break;
    }
    const int by = yb - p.ystart[s];

    const int t    = threadIdx.x;
    const int bm   = blockIdx.x * 128;
    const int bn   = by * 128;
    const int w    = t >> 6, lane = t & 63;
    const int wm   = (w >> 1) * 64, wn = (w & 1) * 64;
    const int quad = lane >> 4, lm = lane & 15;

    // staging map: lane l -> local row = 32w + (l>>2) (+16), phys chunk p=l&3
    const int sr = lane >> 2;
    const int pc = lane & 3;
    const int r0loc = 32 * w + sr;
    const int r1loc = r0loc + 16;
    const int c0 = pc ^ ((r0loc >> 1) & 3);   // global chunk for phys chunk pc
    const int c1 = pc ^ ((r1loc >> 1) & 3);

    const __hip_bfloat16* Ag0 = sg.A  + (size_t)(bm + r0loc) * sg.lda  + c0 * 8;
    const __hip_bfloat16* Ag1 = sg.A  + (size_t)(bm + r1loc) * sg.lda  + c1 * 8;
    const __hip_bfloat16* Bg0 = sg.Bt + (size_t)(bn + r0loc) * sg.ldbt + c0 * 8;
    const __hip_bfloat16* Bg1 = sg.Bt + (size_t)(bn + r1loc) * sg.ldbt + c1 * 8;
    __hip_bfloat16* Al0 = As + (32 * w) * 32;
    __hip_bfloat16* Al1 = As + (32 * w + 16) * 32;
    __hip_bfloat16* Bl0 = Bs + (32 * w) * 32;
    __hip_bfloat16* Bl1 = Bs + (32 * w + 16) * 32;

    floatx4 acc[4][4] = {};

    for (int k0 = 0; k0 < sg.K; k0 += 32) {
        GLDS16(Ag0 + k0, Al0);
        GLDS16(Ag1 + k0, Al1);
        GLDS16(Bg0 + k0, Bl0);
        GLDS16(Bg1 + k0, Bl1);
        __syncthreads();

        short8 af[4], bf[4];
#pragma unroll
        for (int i = 0; i < 4; ++i) {
            const int row = wm + i * 16 + lm;
            af[i] = *(const short8*)&As[row * 32 + ((quad ^ ((row >> 1) & 3)) * 8)];
        }
#pragma unroll
        for (int j = 0; j < 4; ++j) {
            const int row = wn + j * 16 + lm;
            bf[j] = *(const short8*)&Bs[row * 32 + ((quad ^ ((row >> 1) & 3)) * 8)];
        }
#pragma unroll
        for (int i = 0; i < 4; ++i)
#pragma unroll
            for (int j = 0; j < 4; ++j)
                acc[i][j] = __builtin_amdgcn_mfma_f32_16x16x32_bf16(
                    af[i], bf[j], acc[i][j], 0, 0, 0);
        __syncthreads();
    }

#pragma unroll
    for (int i = 0; i < 4; ++i)
#pragma unroll
        for (int reg = 0; reg < 4; ++reg) {
            const int row = bm + wm + i * 16 + quad * 4 + reg;
#pragma unroll
            for (int j = 0; j < 4; ++j) {
                const int col = bn + wn + j * 16 + lm;
                const float v = acc[i][j][reg] + sg.bias[col];
                if (sg.omode == 0) {
                    ((float*)sg.C)[(size_t)row * sg.ldc + col] = v;
                } else if (sg.omode == 1) {
                    ((__hip_bfloat16*)sg.C)[(size_t)row * sg.ldc + col] = __float2bfloat16(v);
                } else {
                    const int h = col / 48;
                    const size_t idx = (size_t)row * 768 + h * 96 +
                                       ((sg.omode == 3) ? 48 : 0) + (col - h * 48);
                    ((__hip_bfloat16*)sg.C)[idx] = __float2bfloat16(v);
                }
            }
        }
}

// =====================================================================
// Fused sampler, 2 queries per 192-thread block (round-5 best config).
// Phase 3: 96 threads/query; (br,h) group of 6 threads; uint4 gathers from
// combined value layout (point row 1536B = [h][br][48ch]); 12 consecutive
// lanes read one contiguous 192B segment (3 cache lines).
// =====================================================================
#define SPP 524

__global__ __launch_bounds__(192) void sampler_kernel(
    const float* __restrict__ off_buf,    // (M, 256) fp32
    const float* __restrict__ logit_top,  // (M, 128)
    const float* __restrict__ logit_bot,  // (M, 128)
    const float* __restrict__ ref_pts,    // (M, 4, 2)
    const int*   __restrict__ ss,         // (4,2) [H,W]
    const int*   __restrict__ lsi,        // (4,)
    const __hip_bfloat16* __restrict__ vcomb,  // (Mv, 768) combined
    __hip_bfloat16* __restrict__ core_top,     // (M, 384) bf16
    __hip_bfloat16* __restrict__ core_bot,     // (M, 384) bf16
    int Lq, int LenIn)
{
    __shared__ float    sA[4][128];   // [q*2+br][e]
    __shared__ unsigned sP[4][SPP];   // packed (bf16 w)<<16 | point

    const int bid = blockIdx.x;
    const int Q0  = bid * 2;
    const int t   = threadIdx.x;

    float gw[2][4];
    int   gp[2][4];
#pragma unroll
    for (int slot = 0; slot < 2; ++slot) {
        const bool active = slot ? (t >= 64) : (t < 128);
        if (!active) continue;
        const int qL = slot;
        const int e  = slot ? (t - 64) : t;
        const int gq = Q0 + qL;
        const int n  = gq / Lq;
        const int l  = (e >> 2) & 3;
        const float2 offv = *(const float2*)&off_buf[(size_t)gq * 256 + 2 * e];
        const float rx = ref_pts[(size_t)(gq * 4 + l) * 2 + 0];
        const float ry = ref_pts[(size_t)(gq * 4 + l) * 2 + 1];
        const int H = ss[2 * l], W = ss[2 * l + 1];
        const int start = lsi[l];

        const float x = (rx + offv.x / (float)W) * (float)W - 0.5f;
        const float y = (ry + offv.y / (float)H) * (float)H - 0.5f;
        const float x0f = floorf(x), y0f = floorf(y);
        const float lx = x - x0f, ly = y - y0f;
        const int ix0 = (int)x0f, iy0 = (int)y0f;
        const int ix1 = ix0 + 1,  iy1 = iy0 + 1;

        const float vx0 = (ix0 >= 0 && ix0 < W) ? 1.f : 0.f;
        const float vx1 = (ix1 >= 0 && ix1 < W) ? 1.f : 0.f;
        const float vy0 = (iy0 >= 0 && iy0 < H) ? 1.f : 0.f;
        const float vy1 = (iy1 >= 0 && iy1 < H) ? 1.f : 0.f;
        const int cx0 = min(max(ix0, 0), W - 1);
        const int cx1 = min(max(ix1, 0), W - 1);
        const int cy0 = min(max(iy0, 0), H - 1);
        const int cy1 = min(max(iy1, 0), H - 1);
        const int base = n * LenIn + start;

        gp[slot][0] = base + cy0 * W + cx0;
        gp[slot][1] = base + cy0 * W + cx1;
        gp[slot][2] = base + cy1 * W + cx0;
        gp[slot][3] = base + cy1 * W + cx1;
        gw[slot][0] = (1.f - lx) * (1.f - ly) * vx0 * vy0;
        gw[slot][1] = lx * (1.f - ly) * vx1 * vy0;
        gw[slot][2] = (1.f - lx) * ly * vx0 * vy1;
        gw[slot][3] = lx * ly * vx1 * vy1;
    }

    // ---- softmax: t<32 -> (q = t>>4, br = (t>>3)&1, h = t&7) ----
    if (t < 32) {
        const int q  = t >> 4;
        const int br = (t >> 3) & 1;
        const int h  = t & 7;
        const float* L = (br ? logit_bot : logit_top) + (size_t)(Q0 + q) * 128 + h * 16;
        float lg[16];
        *(float4*)&lg[0]  = *(const float4*)&L[0];
        *(float4*)&lg[4]  = *(const float4*)&L[4];
        *(float4*)&lg[8]  = *(const float4*)&L[8];
        *(float4*)&lg[12] = *(const float4*)&L[12];
        float m = -1e30f;
#pragma unroll
        for (int j = 0; j < 16; ++j) m = fmaxf(m, lg[j]);
        float ex[16], sum = 0.f;
#pragma unroll
        for (int j = 0; j < 16; ++j) { ex[j] = expf(lg[j] - m); sum += ex[j]; }
        const float inv = 1.f / sum;
#pragma unroll
        for (int j = 0; j < 16; ++j) sA[q * 2 + br][h * 16 + j] = ex[j] * inv;
    }
    __syncthreads();

    // ---- pack premultiplied weights + point indices ----
#pragma unroll
    for (int slot = 0; slot < 2; ++slot) {
        const bool active = slot ? (t >= 64) : (t < 128);
        if (!active) continue;
        const int e = slot ? (t - 64) : t;
        const int pidx = 4 * e + (e >> 4);
#pragma unroll
        for (int br = 0; br < 2; ++br) {
            const float a = sA[slot * 2 + br][e];
#pragma unroll
            for (int k = 0; k < 4; ++k) {
                sP[slot * 2 + br][pidx + k] =
                    ((unsigned)f2bfbits(gw[slot][k] * a) << 16) | (unsigned)gp[slot][k];
            }
        }
    }
    __syncthreads();

    // ---- phase 3: gathers ----
    const int q  = t / 96;
    const int r  = t - q * 96;
    const int g  = r / 6;
    const int m  = r - g * 6;
    const int br = g & 1;
    const int h  = g >> 1;

    const unsigned* P = sP[q * 2 + br];
    const char* vb = (const char*)vcomb + h * 192 + br * 96 + m * 16;

    float a0 = 0.f, a1 = 0.f, a2 = 0.f, a3 = 0.f;
    float a4 = 0.f, a5 = 0.f, a6 = 0.f, a7 = 0.f;
#pragma unroll 4
    for (int lp = 0; lp < 16; ++lp) {
        const int ib = 65 * h + 4 * lp;
#pragma unroll
        for (int k = 0; k < 4; ++k) {
            const unsigned u = P[ib + k];
            const float wv = __uint_as_float(u & 0xffff0000u);
            const unsigned pt = u & 0x3fffu;
            const uint4 v = *(const uint4*)(vb + pt * 1536u);
            a0 = fmaf(wv, bflo(v.x), a0);
            a1 = fmaf(wv, bfhi(v.x), a1);
            a2 = fmaf(wv, bflo(v.y), a2);
            a3 = fmaf(wv, bfhi(v.y), a3);
            a4 = fmaf(wv, bflo(v.z), a4);
            a5 = fmaf(wv, bfhi(v.z), a5);
            a6 = fmaf(wv, bflo(v.w), a6);
            a7 = fmaf(wv, bfhi(v.w), a7);
        }
    }
    uint4 o;
    o.x = pack2(a0, a1); o.y = pack2(a2, a3);
    o.z = pack2(a4, a5); o.w = pack2(a6, a7);
    __hip_bfloat16* dst = br ? core_bot : core_top;
    *(uint4*)&dst[(size_t)(Q0 + q) * DM + h * HD + m * 8] = o;
}

// =====================================================================
// Host launcher
// =====================================================================
extern "C" void kernel_launch(void* const* d_in, const int* in_sizes, int n_in,
                              void* d_out, int out_size, void* d_ws, size_t ws_size,
                              hipStream_t stream) {
    const float* query   = (const float*)d_in[0];
    const float* refpts  = (const float*)d_in[1];
    const float* flat    = (const float*)d_in[2];
    const int*   ss      = (const int*)d_in[3];
    const int*   lsi     = (const int*)d_in[4];
    const float* W_off   = (const float*)d_in[5];
    const float* b_off   = (const float*)d_in[6];
    const float* W_attn  = (const float*)d_in[7];
    const float* b_attn  = (const float*)d_in[8];
    const float* W_val   = (const float*)d_in[9];
    const float* b_val   = (const float*)d_in[10];
    const float* W_out   = (const float*)d_in[11];
    const float* b_out   = (const float*)d_in[12];
    const float* W_attn_zd = (const float*)d_in[13];
    const float* b_attn_zd = (const float*)d_in[14];
    const float* W_val_zd  = (const float*)d_in[15];
    const float* b_val_zd  = (const float*)d_in[16];
    const float* W_out_zd  = (const float*)d_in[17];
    const float* b_out_zd  = (const float*)d_in[18];

    const int Lq    = in_sizes[0] / (2 * DM);   // 5440
    const int LenIn = in_sizes[2] / (2 * DM);   // 5440
    const int M  = 2 * Lq;      // 10880
    const int Mv = 2 * LenIn;   // 10880

    float* out = (float*)d_out;

    // ---- workspace layout ----
    float* ws      = (float*)d_ws;
    float* off_buf = ws;                               // M*256 f32
    float* lt      = off_buf + (size_t)M * 256;        // M*128 f32
    float* lb      = lt + (size_t)M * 128;             // M*128 f32
    __hip_bfloat16* q_bf  = (__hip_bfloat16*)(lb + (size_t)M * 128); // M*384
    __hip_bfloat16* f_bf  = q_bf + (size_t)M * 384;    // Mv*384
    __hip_bfloat16* vcomb = f_bf + (size_t)Mv * 384;   // Mv*768 combined
    __hip_bfloat16* ct    = vcomb + (size_t)Mv * 768;  // M*384
    __hip_bfloat16* cb    = ct + (size_t)M * 384;      // M*384
    __hip_bfloat16* wtb   = cb + (size_t)M * 384;      // weights

    // ---- prep params (7 weight transposes incl. W_off) ----
    PrepParams pp;
    pp.q = query; pp.f = flat;
    pp.q_bf = q_bf; pp.f_bf = f_bf;
    const float* srcs[7] = {W_attn, W_attn_zd, W_val, W_val_zd, W_out, W_out_zd, W_off};
    const int Ks[7] = {256, 384, 256, 384, 384, 384, 256};
    const int Ns[7] = {128, 128, 384, 384, 256, 128, 256};
    __hip_bfloat16* dsts[7];
    int off = 0;
    for (int i = 0; i < 7; ++i) {
        pp.wsrc[i] = srcs[i]; pp.K[i] = Ks[i]; pp.N[i] = Ns[i];
        pp.off[i] = off;
        dsts[i] = wtb + off;
        pp.wdst[i] = dsts[i];
        off += Ks[i] * Ns[i];
    }
    pp.off[7] = off;
    pp.nQ4 = M * DM / 4;
    pp.nF4 = Mv * DM / 4;
    pp.total = pp.nQ4 + pp.nF4 + off;

    const dim3 blk(256);
    const int mg = M / 128;   // 85

    prep_kernel<<<dim3((pp.total + 255) / 256), blk, 0, stream>>>(pp);

    // ---- MEGA-GEMM 1: off + logits + values(combined scatter), grid (85,10)
    {
        SegParams p;
        p.seg[0] = { q_bf, DM, dsts[6], 256, b_off,    off_buf, 256, 256, 0 }; // y0-1
        p.seg[1] = { q_bf, DM, dsts[0], 256, b_attn,   lt,      128, 256, 0 }; // y2
        p.seg[2] = { q_bf, DM, dsts[1], 384, b_attn_zd,lb,      128, 384, 0 }; // y3
        p.seg[3] = { f_bf, DM, dsts[2], 256, b_val,    vcomb,   0,   256, 2 }; // y4-6 top
        p.seg[4] = { f_bf, DM, dsts[3], 384, b_val_zd, vcomb,   0,   384, 3 }; // y7-9 bot
        p.ystart[0] = 0; p.ystart[1] = 2; p.ystart[2] = 3;
        p.ystart[3] = 4; p.ystart[4] = 7;
        p.nseg = 5;
        gemm_seg_kernel<<<dim3(mg, 10), blk, 0, stream>>>(p);
    }

    // ---- sampler: 2 queries per 192-thread block ----
    sampler_kernel<<<dim3(M / 2), dim3(192), 0, stream>>>(
        off_buf, lt, lb, refpts, ss, lsi, vcomb, ct, cb, Lq, LenIn);

    // ---- MEGA-GEMM 2: output projections, grid (85,3) ----
    {
        SegParams p;
        p.seg[0] = { ct, DM, dsts[4], 384, b_out,    out,      DM, 384, 0 }; // y0-1
        p.seg[1] = { cb, DM, dsts[5], 384, b_out_zd, out + U2, DM, 384, 0 }; // y2
        p.ystart[0] = 0; p.ystart[1] = 2;
        p.nseg = 2;
        gemm_seg_kernel<<<dim3(mg, 3), blk, 0, stream>>>(p);
    }
}